// Round 3
// baseline (508.493 us; speedup 1.0000x reference)
//
#include <hip/hip_runtime.h>
#include <hip/hip_bf16.h>

#define BB 16384
#define EE 16
#define HH 256
#define CC 64
#define XD 320   // H + C
#define FH 1024  // 4H
#define CNTP 16  // cnt padding stride (one counter per 64B line)

typedef __attribute__((ext_vector_type(8))) short short8;
typedef __attribute__((ext_vector_type(4))) float f32x4;

__device__ inline unsigned short bfu(float x) {
    union { __hip_bfloat16 b; unsigned short u; } c;
    c.b = __float2bfloat16(x);
    return c.u;
}

// ---------------- anchor normalize ----------------
__global__ void anorm_kernel(const float* __restrict__ anchor, float* __restrict__ anorm) {
    int lane = threadIdx.x & 63;
    int wv = threadIdx.x >> 6;
    for (int e = wv; e < EE; e += 4) {
        float a = anchor[e * CC + lane];
        float s = a * a;
        #pragma unroll
        for (int off = 1; off < 64; off <<= 1) s += __shfl_xor(s, off, 64);
        anorm[e * CC + lane] = a / fmaxf(sqrtf(s), 1e-8f);
    }
}

// ---------------- router: 16 tokens x 16 experts per block, no atomics ----------------
__global__ __launch_bounds__(256) void router_kernel(
    const float* __restrict__ code_emb, const float* __restrict__ gumbel,
    const float* __restrict__ anorm,
    float* __restrict__ topw, int* __restrict__ tope)
{
    __shared__ float an_s[EE][68];
    __shared__ float ce_s[16][68];
    __shared__ float inrm[16];
    const int tid = threadIdx.x;

    // stage normalized anchors (1024 f32) and 16 ce rows (1024 f32)
    {
        int idx = tid * 4;
        int r = idx >> 6, k = idx & 63;
        *(float4*)&an_s[r][k] = *(const float4*)&anorm[idx];
        *(float4*)&ce_s[r][k] = *(const float4*)&code_emb[blockIdx.x * 1024 + idx];
    }
    __syncthreads();

    const int tok = tid >> 4;
    const int e = tid & 15;
    if (e == 0) {
        float s = 0.f;
        #pragma unroll
        for (int k = 0; k < 64; ++k) { float c = ce_s[tok][k]; s += c * c; }
        inrm[tok] = 0.125f / fmaxf(sqrtf(s), 1e-8f);
    }
    __syncthreads();

    float dot = 0.f;
    #pragma unroll
    for (int k = 0; k < 64; ++k) dot += ce_s[tok][k] * an_s[e][k];

    const int b = blockIdx.x * 16 + tok;
    float z = (dot * inrm[tok] + gumbel[b * EE + e]) * 2.0f;  // /TAU, TAU=0.5

    // softmax over the 16-lane group
    float m = z;
    #pragma unroll
    for (int off = 1; off < 16; off <<= 1) m = fmaxf(m, __shfl_xor(m, off, 64));
    float p = expf(z - m);
    float s = p;
    #pragma unroll
    for (int off = 1; off < 16; off <<= 1) s += __shfl_xor(s, off, 64);
    float w = p / s;

    // top-2 (lowest-index tie-break), redundant across the 16-lane group
    const int lbase = (tid & 63) & 48;
    float best = -1.f, second = -1.f;
    int bi = 0, si = 0;
    #pragma unroll
    for (int j = 0; j < EE; ++j) {
        float wj = __shfl(w, lbase + j, 64);
        if (wj > best) { second = best; si = bi; best = wj; bi = j; }
        else if (wj > second) { second = wj; si = j; }
    }
    if (e == 0) {
        topw[b * 2] = best;       tope[b * 2] = bi;
        topw[b * 2 + 1] = second; tope[b * 2 + 1] = si;
    }
}

// ---------------- counting-sort assignment: 512 pairs per block ----------------
__global__ __launch_bounds__(256) void assign_kernel(
    const int* __restrict__ tope, int* __restrict__ list, int* __restrict__ cnt)
{
    __shared__ int lcnt[EE];
    __shared__ int base[EE];
    const int tid = threadIdx.x;
    if (tid < EE) lcnt[tid] = 0;
    __syncthreads();
    const int p0 = blockIdx.x * 512;
    const int e0 = tope[p0 + tid];
    const int e1 = tope[p0 + 256 + tid];
    const int r0 = atomicAdd(&lcnt[e0], 1);
    const int r1 = atomicAdd(&lcnt[e1], 1);
    __syncthreads();
    if (tid < EE) base[tid] = atomicAdd(&cnt[tid * CNTP], lcnt[tid]);
    __syncthreads();
    list[e0 * BB + base[e0] + r0] = p0 + tid;
    list[e1 * BB + base[e1] + r1] = p0 + 256 + tid;
}

// ---------------- weight conversion f32 -> bf16 ----------------
__global__ void convert_w_kernel(const float* __restrict__ W1, const float* __restrict__ W2,
                                 __hip_bfloat16* __restrict__ W1bf, __hip_bfloat16* __restrict__ W2bf) {
    int i = blockIdx.x * blockDim.x + threadIdx.x;
    const int n1 = EE * FH * XD / 4;
    const int n2 = EE * HH * FH / 4;
    if (i < n1) {
        float4 v = ((const float4*)W1)[i];
        ushort4 o; o.x = bfu(v.x); o.y = bfu(v.y); o.z = bfu(v.z); o.w = bfu(v.w);
        ((ushort4*)W1bf)[i] = o;
    } else if (i < n1 + n2) {
        int j = i - n1;
        float4 v = ((const float4*)W2)[j];
        ushort4 o; o.x = bfu(v.x); o.y = bfu(v.y); o.z = bfu(v.z); o.w = bfu(v.w);
        ((ushort4*)W2bf)[j] = o;
    }
}

// ---------------- x = concat(h, code_emb) -> bf16 ----------------
__global__ void convert_x_kernel(const float* __restrict__ h, const float* __restrict__ ce,
                                 __hip_bfloat16* __restrict__ xbf) {
    int i = blockIdx.x * blockDim.x + threadIdx.x;  // group of 4 elements
    const int n = BB * XD / 4;
    if (i >= n) return;
    int i4 = i * 4;
    int b = i4 / XD;
    int c = i4 % XD;
    float4 v;
    if (c < HH) v = *(const float4*)&h[b * HH + c];
    else        v = *(const float4*)&ce[b * CC + (c - HH)];
    ushort4 o; o.x = bfu(v.x); o.y = bfu(v.y); o.z = bfu(v.z); o.w = bfu(v.w);
    ((ushort4*)xbf)[i] = o;
}

// ---------------- aux loss (deterministic reduction) ----------------
__global__ __launch_bounds__(256) void aux_kernel(const float* __restrict__ topw,
                                                  const int* __restrict__ tope,
                                                  float* __restrict__ out) {
    __shared__ float ls[256][EE + 1];
    __shared__ float counts[EE];
    int tid = threadIdx.x;
    #pragma unroll
    for (int e = 0; e < EE; ++e) ls[tid][e] = 0.f;
    for (int i = tid; i < 2 * BB; i += 256) ls[tid][tope[i]] += topw[i];
    __syncthreads();
    if (tid < EE) {
        float s = 0.f;
        for (int r = 0; r < 256; ++r) s += ls[r][tid];
        counts[tid] = s;
    }
    __syncthreads();
    if (tid == 0) {
        float total = 0.f;
        for (int e = 0; e < EE; ++e) total += counts[e];
        float mean = total / EE;
        float var = 0.f;
        for (int e = 0; e < EE; ++e) { float d = counts[e] - mean; var += d * d; }
        var /= (EE - 1);
        float ent = 0.f;
        for (int e = 0; e < EE; ++e) { float ld = counts[e] / total; ent -= ld * logf(ld + 1e-12f); }
        out[(size_t)BB * HH] = 0.5f * (sqrtf(var) + ent);
    }
}

// ---------------- fused sparse MoE MLP, wave-independent strips ----------------
// grid (E, 40), 256 threads. 64-token tile per block; each wave owns 16 tokens
// and computes the full 256-dim output for them. No barriers in the K-loop:
// the hid transpose goes through a per-wave LDS buffer (same-wave ds ordering).
__global__ __launch_bounds__(256, 2) void moe_kernel(
    const __hip_bfloat16* __restrict__ xbf,
    const __hip_bfloat16* __restrict__ W1bf,
    const __hip_bfloat16* __restrict__ W2bf,
    const float* __restrict__ b1, const float* __restrict__ b2,
    const int* __restrict__ list, const int* __restrict__ cnt,
    const float* __restrict__ topw,
    float* __restrict__ tmp)
{
    __shared__ __hip_bfloat16 xs[64][328];     // 656B pitch: 16B-aligned, == 16 mod 128 -> 2-way max
    __shared__ __hip_bfloat16 hs[4][16][72];   // per-wave transpose buffer, 144B pitch
    const int e = blockIdx.x;
    const int n = cnt[e * CNTP];
    const int tid = threadIdx.x;
    const int lane = tid & 63;
    const int wv = tid >> 6;     // 0..3: wave owns tokens [wv*16, wv*16+16)
    const int l15 = lane & 15;
    const int kg = lane >> 4;    // 0..3: k-slice group

    const __hip_bfloat16* w1e = W1bf + (size_t)e * FH * XD;
    const __hip_bfloat16* w2e = W2bf + (size_t)e * HH * FH;

    for (int tile = blockIdx.y; tile * 64 < n; tile += gridDim.y) {
        const int base = tile * 64;
        const int nv = min(64, n - base);

        // cooperative gather of 64 x-rows: 4 threads per row, 80 bf16 each
        {
            int row = tid >> 2, part = tid & 3;
            ulonglong2* dst = (ulonglong2*)&xs[row][part * 80];
            if (row < nv) {
                int pair = list[e * BB + base + row];
                const ulonglong2* src = (const ulonglong2*)(xbf + (size_t)(pair >> 1) * XD + part * 80);
                #pragma unroll
                for (int i = 0; i < 10; ++i) dst[i] = src[i];
            } else {
                ulonglong2 zz; zz.x = 0ull; zz.y = 0ull;
                #pragma unroll
                for (int i = 0; i < 10; ++i) dst[i] = zz;
            }
        }
        __syncthreads();

        const int trow = wv * 16;

        f32x4 acc[16];
        #pragma unroll
        for (int nf = 0; nf < 16; ++nf) acc[nf] = (f32x4){0.f, 0.f, 0.f, 0.f};

        for (int oc = 0; oc < 16; ++oc) {
            // GEMM1: pre[16 tok][64 o-cols], K=320 (wave-local)
            f32x4 pre[4];
            #pragma unroll
            for (int nf = 0; nf < 4; ++nf) pre[nf] = (f32x4){0.f, 0.f, 0.f, 0.f};
            const __hip_bfloat16* w1c = w1e + (size_t)(oc * 64 + l15) * XD + kg * 8;
            #pragma unroll
            for (int ks = 0; ks < 10; ++ks) {
                short8 a = *(const short8*)&xs[trow + l15][ks * 32 + kg * 8];
                #pragma unroll
                for (int nf = 0; nf < 4; ++nf) {
                    short8 bfrag = *(const short8*)(w1c + (size_t)(nf * 16) * XD + ks * 32);
                    pre[nf] = __builtin_amdgcn_mfma_f32_16x16x32_bf16(a, bfrag, pre[nf], 0, 0, 0);
                }
            }
            // bias + exact gelu -> per-wave hs (transpose via LDS, same-wave ordering)
            #pragma unroll
            for (int nf = 0; nf < 4; ++nf) {
                float b1v = b1[e * FH + oc * 64 + nf * 16 + l15];
                #pragma unroll
                for (int r = 0; r < 4; ++r) {
                    float v = pre[nf][r] + b1v;
                    float gl = 0.5f * v * (1.0f + erff(v * 0.70710678118654752f));
                    hs[wv][kg * 4 + r][nf * 16 + l15] = __float2bfloat16(gl);
                }
            }
            // GEMM2: acc[16 tok][256 d] += hid @ W2^T over this oc's K=64 slice
            const __hip_bfloat16* w2c = w2e + (size_t)l15 * FH + oc * 64 + kg * 8;
            #pragma unroll
            for (int ks = 0; ks < 2; ++ks) {
                short8 a = *(const short8*)&hs[wv][l15][ks * 32 + kg * 8];
                #pragma unroll
                for (int nf = 0; nf < 16; ++nf) {
                    short8 bfrag = *(const short8*)(w2c + (size_t)(nf * 16) * FH + ks * 32);
                    acc[nf] = __builtin_amdgcn_mfma_f32_16x16x32_bf16(a, bfrag, acc[nf], 0, 0, 0);
                }
            }
        }

        // epilogue: +b2, *routing weight, scatter to per-pair scratch
        #pragma unroll
        for (int r = 0; r < 4; ++r) {
            int row = trow + kg * 4 + r;
            if (row < nv) {
                int pair = list[e * BB + base + row];
                float w = topw[pair];
                float* dst = tmp + (size_t)pair * HH;
                #pragma unroll
                for (int nf = 0; nf < 16; ++nf) {
                    int d = nf * 16 + l15;
                    dst[d] = w * (acc[nf][r] + b2[e * HH + d]);
                }
            }
        }
        __syncthreads();  // protect xs before next tile's gather (rare multi-tile case)
    }
}

// ---------------- combine the two expert slots ----------------
__global__ void combine_kernel(const float* __restrict__ tmp, float* __restrict__ out) {
    int i = blockIdx.x * blockDim.x + threadIdx.x;  // float4 index over [B*256/4)
    int b = i >> 6;
    int d4 = i & 63;
    const float4* t0 = (const float4*)(tmp + (size_t)b * 512);
    float4 a = t0[d4];
    float4 c = t0[64 + d4];
    float4 o;
    o.x = a.x + c.x; o.y = a.y + c.y; o.z = a.z + c.z; o.w = a.w + c.w;
    ((float4*)out)[i] = o;
}

extern "C" void kernel_launch(void* const* d_in, const int* in_sizes, int n_in,
                              void* d_out, int out_size, void* d_ws, size_t ws_size,
                              hipStream_t stream) {
    const float* h   = (const float*)d_in[0];
    const float* ce  = (const float*)d_in[1];
    const float* anc = (const float*)d_in[2];
    const float* W1  = (const float*)d_in[3];
    const float* b1  = (const float*)d_in[4];
    const float* W2  = (const float*)d_in[5];
    const float* b2  = (const float*)d_in[6];
    const float* gum = (const float*)d_in[7];
    float* out = (float*)d_out;

    char* ws = (char*)d_ws;
    size_t off = 0;
    auto alloc = [&](size_t bytes) {
        char* p = ws + off;
        off = (off + bytes + 255) & ~(size_t)255;
        return p;
    };
    __hip_bfloat16* W1bf = (__hip_bfloat16*)alloc((size_t)EE * FH * XD * 2);
    __hip_bfloat16* W2bf = (__hip_bfloat16*)alloc((size_t)EE * HH * FH * 2);
    __hip_bfloat16* xbf  = (__hip_bfloat16*)alloc((size_t)BB * XD * 2);
    float* tmp  = (float*)alloc((size_t)BB * 2 * HH * 4);
    float* topw = (float*)alloc((size_t)BB * 2 * 4);
    int*   tope = (int*)alloc((size_t)BB * 2 * 4);
    int*   list = (int*)alloc((size_t)EE * BB * 4);
    int*   cnt  = (int*)alloc(EE * CNTP * 4);
    float* anorm = (float*)alloc(EE * CC * 4);

    hipMemsetAsync(cnt, 0, EE * CNTP * 4, stream);
    anorm_kernel<<<1, 256, 0, stream>>>(anc, anorm);
    router_kernel<<<BB / 16, 256, 0, stream>>>(ce, gum, anorm, topw, tope);
    assign_kernel<<<2 * BB / 512, 256, 0, stream>>>(tope, list, cnt);
    convert_w_kernel<<<((EE * FH * XD + EE * HH * FH) / 4 + 255) / 256, 256, 0, stream>>>(W1, W2, W1bf, W2bf);
    convert_x_kernel<<<(BB * XD / 4 + 255) / 256, 256, 0, stream>>>(h, ce, xbf);
    aux_kernel<<<1, 256, 0, stream>>>(topw, tope, out);
    moe_kernel<<<dim3(EE, 40), 256, 0, stream>>>(xbf, W1bf, W2bf, b1, b2, list, cnt, topw, tmp);
    combine_kernel<<<(BB * HH / 4) / 256, 256, 0, stream>>>(tmp, out);
}

// Round 4
// 211.006 us; speedup vs baseline: 2.4099x; 2.4099x over previous
//
#include <hip/hip_runtime.h>
#include <hip/hip_bf16.h>

#define BB 16384
#define EE 16
#define HH 256
#define CC 64
#define XD 320   // H + C
#define FH 1024  // 4H
#define CNTP 16  // cnt padding stride (one counter per 64B line)

typedef __attribute__((ext_vector_type(8))) short short8;
typedef __attribute__((ext_vector_type(4))) float f32x4;

__device__ inline unsigned short bfu(float x) {
    union { __hip_bfloat16 b; unsigned short u; } c;
    c.b = __float2bfloat16(x);
    return c.u;
}

// raw workgroup barrier: drains LDS ops only, leaves global loads in flight
__device__ inline void wg_barrier() {
    asm volatile("s_waitcnt lgkmcnt(0)" ::: "memory");
    __builtin_amdgcn_s_barrier();
    asm volatile("" ::: "memory");
}

// ---------------- anchor normalize ----------------
__global__ void anorm_kernel(const float* __restrict__ anchor, float* __restrict__ anorm) {
    int lane = threadIdx.x & 63;
    int wv = threadIdx.x >> 6;
    for (int e = wv; e < EE; e += 4) {
        float a = anchor[e * CC + lane];
        float s = a * a;
        #pragma unroll
        for (int off = 1; off < 64; off <<= 1) s += __shfl_xor(s, off, 64);
        anorm[e * CC + lane] = a / fmaxf(sqrtf(s), 1e-8f);
    }
}

// ---------------- router: 16 tokens x 16 experts per block, no atomics ----------------
__global__ __launch_bounds__(256) void router_kernel(
    const float* __restrict__ code_emb, const float* __restrict__ gumbel,
    const float* __restrict__ anorm,
    float* __restrict__ topw, int* __restrict__ tope)
{
    __shared__ float an_s[EE][68];
    __shared__ float ce_s[16][68];
    __shared__ float inrm[16];
    const int tid = threadIdx.x;

    {
        int idx = tid * 4;
        int r = idx >> 6, k = idx & 63;
        *(float4*)&an_s[r][k] = *(const float4*)&anorm[idx];
        *(float4*)&ce_s[r][k] = *(const float4*)&code_emb[blockIdx.x * 1024 + idx];
    }
    __syncthreads();

    const int tok = tid >> 4;
    const int e = tid & 15;
    if (e == 0) {
        float s = 0.f;
        #pragma unroll
        for (int k = 0; k < 64; ++k) { float c = ce_s[tok][k]; s += c * c; }
        inrm[tok] = 0.125f / fmaxf(sqrtf(s), 1e-8f);
    }
    __syncthreads();

    float dot = 0.f;
    #pragma unroll
    for (int k = 0; k < 64; ++k) dot += ce_s[tok][k] * an_s[e][k];

    const int b = blockIdx.x * 16 + tok;
    float z = (dot * inrm[tok] + gumbel[b * EE + e]) * 2.0f;  // /TAU, TAU=0.5

    float m = z;
    #pragma unroll
    for (int off = 1; off < 16; off <<= 1) m = fmaxf(m, __shfl_xor(m, off, 64));
    float p = expf(z - m);
    float s = p;
    #pragma unroll
    for (int off = 1; off < 16; off <<= 1) s += __shfl_xor(s, off, 64);
    float w = p / s;

    const int lbase = (tid & 63) & 48;
    float best = -1.f, second = -1.f;
    int bi = 0, si = 0;
    #pragma unroll
    for (int j = 0; j < EE; ++j) {
        float wj = __shfl(w, lbase + j, 64);
        if (wj > best) { second = best; si = bi; best = wj; bi = j; }
        else if (wj > second) { second = wj; si = j; }
    }
    if (e == 0) {
        topw[b * 2] = best;       tope[b * 2] = bi;
        topw[b * 2 + 1] = second; tope[b * 2 + 1] = si;
    }
}

// ---------------- counting-sort assignment: 512 pairs per block ----------------
__global__ __launch_bounds__(256) void assign_kernel(
    const int* __restrict__ tope, int* __restrict__ list, int* __restrict__ cnt)
{
    __shared__ int lcnt[EE];
    __shared__ int base[EE];
    const int tid = threadIdx.x;
    if (tid < EE) lcnt[tid] = 0;
    __syncthreads();
    const int p0 = blockIdx.x * 512;
    const int e0 = tope[p0 + tid];
    const int e1 = tope[p0 + 256 + tid];
    const int r0 = atomicAdd(&lcnt[e0], 1);
    const int r1 = atomicAdd(&lcnt[e1], 1);
    __syncthreads();
    if (tid < EE) base[tid] = atomicAdd(&cnt[tid * CNTP], lcnt[tid]);
    __syncthreads();
    list[e0 * BB + base[e0] + r0] = p0 + tid;
    list[e1 * BB + base[e1] + r1] = p0 + 256 + tid;
}

// ---------------- weight conversion f32 -> bf16 ----------------
__global__ void convert_w_kernel(const float* __restrict__ W1, const float* __restrict__ W2,
                                 __hip_bfloat16* __restrict__ W1bf, __hip_bfloat16* __restrict__ W2bf) {
    int i = blockIdx.x * blockDim.x + threadIdx.x;
    const int n1 = EE * FH * XD / 4;
    const int n2 = EE * HH * FH / 4;
    if (i < n1) {
        float4 v = ((const float4*)W1)[i];
        ushort4 o; o.x = bfu(v.x); o.y = bfu(v.y); o.z = bfu(v.z); o.w = bfu(v.w);
        ((ushort4*)W1bf)[i] = o;
    } else if (i < n1 + n2) {
        int j = i - n1;
        float4 v = ((const float4*)W2)[j];
        ushort4 o; o.x = bfu(v.x); o.y = bfu(v.y); o.z = bfu(v.z); o.w = bfu(v.w);
        ((ushort4*)W2bf)[j] = o;
    }
}

// ---------------- x = concat(h, code_emb) -> bf16 ----------------
__global__ void convert_x_kernel(const float* __restrict__ h, const float* __restrict__ ce,
                                 __hip_bfloat16* __restrict__ xbf) {
    int i = blockIdx.x * blockDim.x + threadIdx.x;
    const int n = BB * XD / 4;
    if (i >= n) return;
    int i4 = i * 4;
    int b = i4 / XD;
    int c = i4 % XD;
    float4 v;
    if (c < HH) v = *(const float4*)&h[b * HH + c];
    else        v = *(const float4*)&ce[b * CC + (c - HH)];
    ushort4 o; o.x = bfu(v.x); o.y = bfu(v.y); o.z = bfu(v.z); o.w = bfu(v.w);
    ((ushort4*)xbf)[i] = o;
}

// ---------------- aux loss (deterministic reduction) ----------------
__global__ __launch_bounds__(256) void aux_kernel(const float* __restrict__ topw,
                                                  const int* __restrict__ tope,
                                                  float* __restrict__ out) {
    __shared__ float ls[256][EE + 1];
    __shared__ float counts[EE];
    int tid = threadIdx.x;
    #pragma unroll
    for (int e = 0; e < EE; ++e) ls[tid][e] = 0.f;
    for (int i = tid; i < 2 * BB; i += 256) ls[tid][tope[i]] += topw[i];
    __syncthreads();
    if (tid < EE) {
        float s = 0.f;
        for (int r = 0; r < 256; ++r) s += ls[r][tid];
        counts[tid] = s;
    }
    __syncthreads();
    if (tid == 0) {
        float total = 0.f;
        for (int e = 0; e < EE; ++e) total += counts[e];
        float mean = total / EE;
        float var = 0.f;
        for (int e = 0; e < EE; ++e) { float d = counts[e] - mean; var += d * d; }
        var /= (EE - 1);
        float ent = 0.f;
        for (int e = 0; e < EE; ++e) { float ld = counts[e] / total; ent -= ld * logf(ld + 1e-12f); }
        out[(size_t)BB * HH] = 0.5f * (sqrtf(var) + ent);
    }
}

// ---------------- fused sparse MoE MLP (R2 topology + pipelined) ----------------
// grid (E, 32), 256 threads. Per 64-token tile: waves split N; W2(oc) issued
// early, W1(oc+1) prefetched into regs (double-buffered via 2x unroll);
// hs double-buffered -> ONE raw barrier per oc, no vmcnt drains.
__global__ __launch_bounds__(256, 2) void moe_kernel(
    const __hip_bfloat16* __restrict__ xbf,
    const __hip_bfloat16* __restrict__ W1bf,
    const __hip_bfloat16* __restrict__ W2bf,
    const float* __restrict__ b1, const float* __restrict__ b2,
    const int* __restrict__ list, const int* __restrict__ cnt,
    const float* __restrict__ topw,
    float* __restrict__ tmp)
{
    __shared__ __hip_bfloat16 xs[64 * 320];      // XOR-swizzled, linear pitch
    __shared__ __hip_bfloat16 hsbufs[2][64 * 64]; // double-buffered, XOR-swizzled
    const int e = blockIdx.x;
    const int n = cnt[e * CNTP];
    const int tid = threadIdx.x;
    const int lane = tid & 63;
    const int wv = tid >> 6;     // 0..3
    const int l15 = lane & 15;
    const int kg = lane >> 4;    // 0..3
    const int lr7 = l15 & 7;

    const __hip_bfloat16* w1e = W1bf + (size_t)e * FH * XD;
    const __hip_bfloat16* w2e = W2bf + (size_t)e * HH * FH;

    // W1 fragment row base for this thread (col group = wv*16+l15)
    const __hip_bfloat16* w1r = w1e + (size_t)(wv * 16 + l15) * XD + kg * 8;
    const __hip_bfloat16* w2r = w2e + (size_t)(wv * 64 + l15) * FH + kg * 8;

    f32x4 acc[4][4];

    // per-oc body: GEMM1 with fcur, prefetch fnxt for oc+1, GELU->hsbuf, barrier, GEMM2
    auto ocbody = [&](short8 (&fcur)[10], short8 (&fnxt)[10],
                      float& b1cur, float& b1nxt,
                      __hip_bfloat16* hsbuf, int oc) {
        // early-issue W2(oc) fragments (consumed after the barrier)
        short8 f2[8];
        {
            const __hip_bfloat16* w2c = w2r + oc * 64;
            #pragma unroll
            for (int nf = 0; nf < 4; ++nf)
                #pragma unroll
                for (int ks = 0; ks < 2; ++ks)
                    f2[nf * 2 + ks] = *(const short8*)(w2c + (size_t)(nf * 16) * FH + ks * 32);
        }
        // GEMM1: pre[64 tok][16 cols per wave], K=320
        f32x4 pre[4];
        #pragma unroll
        for (int mi = 0; mi < 4; ++mi) pre[mi] = (f32x4){0.f, 0.f, 0.f, 0.f};
        #pragma unroll
        for (int ks = 0; ks < 10; ++ks) {
            #pragma unroll
            for (int mi = 0; mi < 4; ++mi) {
                int rrow = mi * 16 + l15;
                short8 a = *(const short8*)&xs[rrow * 320 + (((ks * 4 + kg) ^ lr7) << 3)];
                pre[mi] = __builtin_amdgcn_mfma_f32_16x16x32_bf16(a, fcur[ks], pre[mi], 0, 0, 0);
            }
        }
        // prefetch W1(oc+1) + b1(oc+1) — in flight across GELU/barrier/GEMM2
        {
            int ocn = (oc + 1) & 15;
            const __hip_bfloat16* w1n = w1r + (size_t)(ocn * 64) * XD;
            #pragma unroll
            for (int ks = 0; ks < 10; ++ks) fnxt[ks] = *(const short8*)(w1n + ks * 32);
            b1nxt = b1[e * FH + ocn * 64 + wv * 16 + l15];
        }
        // bias + tanh-GELU -> hsbuf (swizzled scalar writes)
        {
            const int cgb = 2 * wv + (l15 >> 3);
            #pragma unroll
            for (int mi = 0; mi < 4; ++mi) {
                #pragma unroll
                for (int r = 0; r < 4; ++r) {
                    float v = pre[mi][r] + b1cur;
                    float y = 1.5957691216057308f * v * fmaf(v * v, 0.044715f, 1.0f);
                    float gl = __fdividef(v, 1.0f + __expf(-y));
                    int row = mi * 16 + kg * 4 + r;
                    int cg = cgb ^ (row & 7);
                    hsbuf[row * 64 + (cg << 3) + lr7] = __float2bfloat16(gl);
                }
            }
        }
        wg_barrier();  // hs(oc) visible; also orders vs next oc's hs writes (alt buffer)
        // GEMM2: acc += hid @ W2^T over this oc's K=64 slice
        #pragma unroll
        for (int ks = 0; ks < 2; ++ks) {
            short8 a[4];
            #pragma unroll
            for (int mi = 0; mi < 4; ++mi) {
                int rrow = mi * 16 + l15;
                a[mi] = *(const short8*)&hsbuf[rrow * 64 + (((ks * 4 + kg) ^ lr7) << 3)];
            }
            #pragma unroll
            for (int nf = 0; nf < 4; ++nf)
                #pragma unroll
                for (int mi = 0; mi < 4; ++mi)
                    acc[mi][nf] = __builtin_amdgcn_mfma_f32_16x16x32_bf16(a[mi], f2[nf * 2 + ks], acc[mi][nf], 0, 0, 0);
        }
    };

    // prologue: load W1(0) + b1(0)
    short8 Wa[10], Wb[10];
    float bA, bB;
    #pragma unroll
    for (int ks = 0; ks < 10; ++ks) Wa[ks] = *(const short8*)(w1r + ks * 32);
    bA = b1[e * FH + wv * 16 + l15];

    for (int tile = blockIdx.y; tile * 64 < n; tile += gridDim.y) {
        const int base = tile * 64;
        const int nv = min(64, n - base);

        // gather 64 x-rows into swizzled xs: 4 threads/row, 10x16B each
        {
            int row = tid >> 2, part = tid & 3;
            int pr = list[e * BB + base + min(row, nv - 1)];
            const ulonglong2* src = (const ulonglong2*)(xbf + (size_t)(pr >> 1) * XD) + part * 10;
            int r7 = row & 7;
            #pragma unroll
            for (int i = 0; i < 10; ++i) {
                int u = part * 10 + i;
                *(ulonglong2*)&xs[row * 320 + ((u ^ r7) << 3)] = src[i];
            }
        }
        wg_barrier();  // xs ready

        #pragma unroll
        for (int mi = 0; mi < 4; ++mi)
            #pragma unroll
            for (int nf = 0; nf < 4; ++nf)
                acc[mi][nf] = (f32x4){0.f, 0.f, 0.f, 0.f};

        for (int t = 0; t < 8; ++t) {
            ocbody(Wa, Wb, bA, bB, hsbufs[0], 2 * t);
            ocbody(Wb, Wa, bB, bA, hsbufs[1], 2 * t + 1);
        }
        // after t=7: Wa holds W1(0) again — ready for next tile

        // epilogue: +b2, *routing weight, scatter to per-pair scratch
        #pragma unroll
        for (int r = 0; r < 4; ++r) {
            int row = kg * 4 + r;
            #pragma unroll
            for (int mi = 0; mi < 4; ++mi) {
                int rr = mi * 16 + row;
                if (rr < nv) {
                    int pair = list[e * BB + base + rr];
                    float w = topw[pair];
                    float* dst = tmp + (size_t)pair * HH + wv * 64;
                    #pragma unroll
                    for (int nf = 0; nf < 4; ++nf) {
                        int d = wv * 64 + nf * 16 + l15;
                        dst[nf * 16 + l15] = w * (acc[mi][nf][r] + b2[e * HH + d]);
                    }
                }
            }
        }
        // no extra barrier needed: next gather is ordered by the last oc barrier
    }
}

// ---------------- combine the two expert slots ----------------
__global__ void combine_kernel(const float* __restrict__ tmp, float* __restrict__ out) {
    int i = blockIdx.x * blockDim.x + threadIdx.x;
    int b = i >> 6;
    int d4 = i & 63;
    const float4* t0 = (const float4*)(tmp + (size_t)b * 512);
    float4 a = t0[d4];
    float4 c = t0[64 + d4];
    float4 o;
    o.x = a.x + c.x; o.y = a.y + c.y; o.z = a.z + c.z; o.w = a.w + c.w;
    ((float4*)out)[i] = o;
}

extern "C" void kernel_launch(void* const* d_in, const int* in_sizes, int n_in,
                              void* d_out, int out_size, void* d_ws, size_t ws_size,
                              hipStream_t stream) {
    const float* h   = (const float*)d_in[0];
    const float* ce  = (const float*)d_in[1];
    const float* anc = (const float*)d_in[2];
    const float* W1  = (const float*)d_in[3];
    const float* b1  = (const float*)d_in[4];
    const float* W2  = (const float*)d_in[5];
    const float* b2  = (const float*)d_in[6];
    const float* gum = (const float*)d_in[7];
    float* out = (float*)d_out;

    char* ws = (char*)d_ws;
    size_t off = 0;
    auto alloc = [&](size_t bytes) {
        char* p = ws + off;
        off = (off + bytes + 255) & ~(size_t)255;
        return p;
    };
    __hip_bfloat16* W1bf = (__hip_bfloat16*)alloc((size_t)EE * FH * XD * 2);
    __hip_bfloat16* W2bf = (__hip_bfloat16*)alloc((size_t)EE * HH * FH * 2);
    __hip_bfloat16* xbf  = (__hip_bfloat16*)alloc((size_t)BB * XD * 2);
    float* tmp  = (float*)alloc((size_t)BB * 2 * HH * 4);
    float* topw = (float*)alloc((size_t)BB * 2 * 4);
    int*   tope = (int*)alloc((size_t)BB * 2 * 4);
    int*   list = (int*)alloc((size_t)EE * BB * 4);
    int*   cnt  = (int*)alloc(EE * CNTP * 4);
    float* anorm = (float*)alloc(EE * CC * 4);

    hipMemsetAsync(cnt, 0, EE * CNTP * 4, stream);
    anorm_kernel<<<1, 256, 0, stream>>>(anc, anorm);
    router_kernel<<<BB / 16, 256, 0, stream>>>(ce, gum, anorm, topw, tope);
    assign_kernel<<<2 * BB / 512, 256, 0, stream>>>(tope, list, cnt);
    convert_w_kernel<<<((EE * FH * XD + EE * HH * FH) / 4 + 255) / 256, 256, 0, stream>>>(W1, W2, W1bf, W2bf);
    convert_x_kernel<<<(BB * XD / 4 + 255) / 256, 256, 0, stream>>>(h, ce, xbf);
    aux_kernel<<<1, 256, 0, stream>>>(topw, tope, out);
    moe_kernel<<<dim3(EE, 32), 256, 0, stream>>>(xbf, W1bf, W2bf, b1, b2, list, cnt, topw, tmp);
    combine_kernel<<<(BB * HH / 4) / 256, 256, 0, stream>>>(tmp, out);
}

// Round 5
// 197.218 us; speedup vs baseline: 2.5783x; 1.0699x over previous
//
#include <hip/hip_runtime.h>
#include <hip/hip_bf16.h>

#define BB 16384
#define EE 16
#define HH 256
#define CC 64
#define XD 320   // H + C
#define FH 1024  // 4H
#define CNTP 16  // cnt padding stride (one counter per 64B line)

typedef __attribute__((ext_vector_type(8))) short short8;
typedef __attribute__((ext_vector_type(4))) float f32x4;

// asm global loads: issue position pinned (volatile), result regs early-clobber.
// We do ALL in-K-loop VMEM via these so manual vmcnt counts are exact.
#define GLOAD16(dst, a, OFF) \
    asm volatile("global_load_dwordx4 %0, %1, off offset:" OFF : "=&v"(dst) : "v"(a))
#define GLOADF(dst, a) \
    asm volatile("global_load_dword %0, %1, off" : "=&v"(dst) : "v"(a))
// counted wait + scheduler fence (rule #18: MFMA hoists past asm waitcnt otherwise)
#define VMWAIT(N) do { asm volatile("s_waitcnt vmcnt(" N ")" ::: "memory"); \
                       __builtin_amdgcn_sched_barrier(0); } while (0)

__device__ inline unsigned short bfu(float x) {
    union { __hip_bfloat16 b; unsigned short u; } c;
    c.b = __float2bfloat16(x);
    return c.u;
}

// raw workgroup barrier: drains LDS ops only, leaves global loads in flight
__device__ inline void wg_barrier() {
    asm volatile("s_waitcnt lgkmcnt(0)" ::: "memory");
    __builtin_amdgcn_s_barrier();
    asm volatile("" ::: "memory");
}

// ---------------- anchor normalize ----------------
__global__ void anorm_kernel(const float* __restrict__ anchor, float* __restrict__ anorm) {
    int lane = threadIdx.x & 63;
    int wv = threadIdx.x >> 6;
    for (int e = wv; e < EE; e += 4) {
        float a = anchor[e * CC + lane];
        float s = a * a;
        #pragma unroll
        for (int off = 1; off < 64; off <<= 1) s += __shfl_xor(s, off, 64);
        anorm[e * CC + lane] = a / fmaxf(sqrtf(s), 1e-8f);
    }
}

// ---------------- router: 16 tokens x 16 experts per block, no atomics ----------------
__global__ __launch_bounds__(256) void router_kernel(
    const float* __restrict__ code_emb, const float* __restrict__ gumbel,
    const float* __restrict__ anorm,
    float* __restrict__ topw, int* __restrict__ tope)
{
    __shared__ float an_s[EE][68];
    __shared__ float ce_s[16][68];
    __shared__ float inrm[16];
    const int tid = threadIdx.x;

    {
        int idx = tid * 4;
        int r = idx >> 6, k = idx & 63;
        *(float4*)&an_s[r][k] = *(const float4*)&anorm[idx];
        *(float4*)&ce_s[r][k] = *(const float4*)&code_emb[blockIdx.x * 1024 + idx];
    }
    __syncthreads();

    const int tok = tid >> 4;
    const int e = tid & 15;
    if (e == 0) {
        float s = 0.f;
        #pragma unroll
        for (int k = 0; k < 64; ++k) { float c = ce_s[tok][k]; s += c * c; }
        inrm[tok] = 0.125f / fmaxf(sqrtf(s), 1e-8f);
    }
    __syncthreads();

    float dot = 0.f;
    #pragma unroll
    for (int k = 0; k < 64; ++k) dot += ce_s[tok][k] * an_s[e][k];

    const int b = blockIdx.x * 16 + tok;
    float z = (dot * inrm[tok] + gumbel[b * EE + e]) * 2.0f;  // /TAU, TAU=0.5

    float m = z;
    #pragma unroll
    for (int off = 1; off < 16; off <<= 1) m = fmaxf(m, __shfl_xor(m, off, 64));
    float p = expf(z - m);
    float s = p;
    #pragma unroll
    for (int off = 1; off < 16; off <<= 1) s += __shfl_xor(s, off, 64);
    float w = p / s;

    const int lbase = (tid & 63) & 48;
    float best = -1.f, second = -1.f;
    int bi = 0, si = 0;
    #pragma unroll
    for (int j = 0; j < EE; ++j) {
        float wj = __shfl(w, lbase + j, 64);
        if (wj > best) { second = best; si = bi; best = wj; bi = j; }
        else if (wj > second) { second = wj; si = j; }
    }
    if (e == 0) {
        topw[b * 2] = best;       tope[b * 2] = bi;
        topw[b * 2 + 1] = second; tope[b * 2 + 1] = si;
    }
}

// ---------------- counting-sort assignment: 512 pairs per block ----------------
__global__ __launch_bounds__(256) void assign_kernel(
    const int* __restrict__ tope, int* __restrict__ list, int* __restrict__ cnt)
{
    __shared__ int lcnt[EE];
    __shared__ int base[EE];
    const int tid = threadIdx.x;
    if (tid < EE) lcnt[tid] = 0;
    __syncthreads();
    const int p0 = blockIdx.x * 512;
    const int e0 = tope[p0 + tid];
    const int e1 = tope[p0 + 256 + tid];
    const int r0 = atomicAdd(&lcnt[e0], 1);
    const int r1 = atomicAdd(&lcnt[e1], 1);
    __syncthreads();
    if (tid < EE) base[tid] = atomicAdd(&cnt[tid * CNTP], lcnt[tid]);
    __syncthreads();
    list[e0 * BB + base[e0] + r0] = p0 + tid;
    list[e1 * BB + base[e1] + r1] = p0 + 256 + tid;
}

// ---------------- weight conversion f32 -> bf16 ----------------
__global__ void convert_w_kernel(const float* __restrict__ W1, const float* __restrict__ W2,
                                 __hip_bfloat16* __restrict__ W1bf, __hip_bfloat16* __restrict__ W2bf) {
    int i = blockIdx.x * blockDim.x + threadIdx.x;
    const int n1 = EE * FH * XD / 4;
    const int n2 = EE * HH * FH / 4;
    if (i < n1) {
        float4 v = ((const float4*)W1)[i];
        ushort4 o; o.x = bfu(v.x); o.y = bfu(v.y); o.z = bfu(v.z); o.w = bfu(v.w);
        ((ushort4*)W1bf)[i] = o;
    } else if (i < n1 + n2) {
        int j = i - n1;
        float4 v = ((const float4*)W2)[j];
        ushort4 o; o.x = bfu(v.x); o.y = bfu(v.y); o.z = bfu(v.z); o.w = bfu(v.w);
        ((ushort4*)W2bf)[j] = o;
    }
}

// ---------------- x = concat(h, code_emb) -> bf16 ----------------
__global__ void convert_x_kernel(const float* __restrict__ h, const float* __restrict__ ce,
                                 __hip_bfloat16* __restrict__ xbf) {
    int i = blockIdx.x * blockDim.x + threadIdx.x;
    const int n = BB * XD / 4;
    if (i >= n) return;
    int i4 = i * 4;
    int b = i4 / XD;
    int c = i4 % XD;
    float4 v;
    if (c < HH) v = *(const float4*)&h[b * HH + c];
    else        v = *(const float4*)&ce[b * CC + (c - HH)];
    ushort4 o; o.x = bfu(v.x); o.y = bfu(v.y); o.z = bfu(v.z); o.w = bfu(v.w);
    ((ushort4*)xbf)[i] = o;
}

// ---------------- aux loss: 64-block partial + tiny final (deterministic) ----------------
__global__ __launch_bounds__(256) void aux_partial_kernel(const float* __restrict__ topw,
                                                          const int* __restrict__ tope,
                                                          float* __restrict__ partial) {
    __shared__ float ls[256][EE + 1];
    int tid = threadIdx.x;
    #pragma unroll
    for (int e = 0; e < EE; ++e) ls[tid][e] = 0.f;
    int i0 = blockIdx.x * 512 + tid;
    ls[tid][tope[i0]] += topw[i0];
    ls[tid][tope[i0 + 256]] += topw[i0 + 256];
    __syncthreads();
    if (tid < EE) {
        float s = 0.f;
        for (int r = 0; r < 256; ++r) s += ls[r][tid];
        partial[blockIdx.x * EE + tid] = s;
    }
}

__global__ void aux_final_kernel(const float* __restrict__ partial, float* __restrict__ out) {
    __shared__ float counts[EE];
    int tid = threadIdx.x;
    if (tid < EE) {
        float s = 0.f;
        for (int bk = 0; bk < 64; ++bk) s += partial[bk * EE + tid];
        counts[tid] = s;
    }
    __syncthreads();
    if (tid == 0) {
        float total = 0.f;
        for (int e = 0; e < EE; ++e) total += counts[e];
        float mean = total / EE;
        float var = 0.f;
        for (int e = 0; e < EE; ++e) { float d = counts[e] - mean; var += d * d; }
        var /= (EE - 1);
        float ent = 0.f;
        for (int e = 0; e < EE; ++e) { float ld = counts[e] / total; ent -= ld * logf(ld + 1e-12f); }
        out[(size_t)BB * HH] = 0.5f * (sqrtf(var) + ent);
    }
}

// ---------------- fused sparse MoE MLP (asm-pipelined weights) ----------------
// grid (E, 36), 256 threads. Waves split N. All in-loop VMEM is inline-asm with
// manual counted vmcnt (T3/T4): batch/oc = [8xW2(oc), 10xW1(oc+1), 1xb1(oc+1)];
// wait vmcnt(19) before GEMM1 (drains prev batch), vmcnt(11) before GEMM2
// (drains this oc's W2, leaves next W1+b1 in flight). sched_barrier(0) after
// each wait stops MFMA hoisting (rule #18). hs double-buffered, raw barriers.
__global__ __launch_bounds__(256, 2) void moe_kernel(
    const __hip_bfloat16* __restrict__ xbf,
    const __hip_bfloat16* __restrict__ W1bf,
    const __hip_bfloat16* __restrict__ W2bf,
    const float* __restrict__ b1, const float* __restrict__ b2,
    const int* __restrict__ list, const int* __restrict__ cnt,
    const float* __restrict__ topw,
    __hip_bfloat16* __restrict__ tmp)
{
    __shared__ __hip_bfloat16 xs[64 * 320];
    __shared__ __hip_bfloat16 hsbufs[2][64 * 64];
    const int e = blockIdx.x;
    const int n = cnt[e * CNTP];
    const int tid = threadIdx.x;
    const int lane = tid & 63;
    const int wv = tid >> 6;     // 0..3
    const int l15 = lane & 15;
    const int kg = lane >> 4;    // 0..3
    const int lr7 = l15 & 7;

    const __hip_bfloat16* w1e = W1bf + (size_t)e * FH * XD;
    const __hip_bfloat16* w2e = W2bf + (size_t)e * HH * FH;
    const __hip_bfloat16* w1r = w1e + (size_t)(wv * 16 + l15) * XD + kg * 8;
    const __hip_bfloat16* w2r = w2e + (size_t)(wv * 64 + l15) * FH + kg * 8;
    const float* b1r = b1 + e * FH + wv * 16 + l15;

    for (int tile = blockIdx.y; tile * 64 < n; tile += gridDim.y) {
        const int base = tile * 64;
        const int nv = min(64, n - base);

        // gather 64 x-rows into swizzled xs: 4 threads/row, 10x16B each
        {
            int row = tid >> 2, part = tid & 3;
            int pr = list[e * BB + base + min(row, nv - 1)];
            const ulonglong2* src = (const ulonglong2*)(xbf + (size_t)(pr >> 1) * XD) + part * 10;
            int r7 = row & 7;
            #pragma unroll
            for (int i = 0; i < 10; ++i) {
                int u = part * 10 + i;
                *(ulonglong2*)&xs[row * 320 + ((u ^ r7) << 3)] = src[i];
            }
        }

        // prologue: issue W1(0) + b1(0) via asm (counts included in vmcnt math)
        short8 Wa[10], Wb[10];
        float bA, bB;
        GLOAD16(Wa[0], w1r, "0");   GLOAD16(Wa[1], w1r, "64");
        GLOAD16(Wa[2], w1r, "128"); GLOAD16(Wa[3], w1r, "192");
        GLOAD16(Wa[4], w1r, "256"); GLOAD16(Wa[5], w1r, "320");
        GLOAD16(Wa[6], w1r, "384"); GLOAD16(Wa[7], w1r, "448");
        GLOAD16(Wa[8], w1r, "512"); GLOAD16(Wa[9], w1r, "576");
        GLOADF(bA, b1r);

        const __hip_bfloat16* pW1  = w1r + (size_t)64 * XD;   // -> oc 1
        const __hip_bfloat16* pW2a = w2r;                     // -> oc 0, nf 0
        const __hip_bfloat16* pW2b = w2r + (size_t)16 * FH;
        const __hip_bfloat16* pW2c = w2r + (size_t)32 * FH;
        const __hip_bfloat16* pW2d = w2r + (size_t)48 * FH;
        const float* pb1 = b1r + 64;                          // -> oc 1

        wg_barrier();  // xs ready

        f32x4 acc[4][4];
        #pragma unroll
        for (int mi = 0; mi < 4; ++mi)
            #pragma unroll
            for (int nf = 0; nf < 4; ++nf)
                acc[mi][nf] = (f32x4){0.f, 0.f, 0.f, 0.f};

        auto ocbody = [&](short8 (&Wc)[10], short8 (&Wn)[10],
                          float& b1c, float& b1n, __hip_bfloat16* hsbuf) {
            // issue W2(oc): 8 loads (oldest in batch)
            short8 f2[8];
            GLOAD16(f2[0], pW2a, "0"); GLOAD16(f2[1], pW2a, "64");
            GLOAD16(f2[2], pW2b, "0"); GLOAD16(f2[3], pW2b, "64");
            GLOAD16(f2[4], pW2c, "0"); GLOAD16(f2[5], pW2c, "64");
            GLOAD16(f2[6], pW2d, "0"); GLOAD16(f2[7], pW2d, "64");
            // issue W1(oc+1) + b1(oc+1): 11 loads (newest in batch)
            GLOAD16(Wn[0], pW1, "0");   GLOAD16(Wn[1], pW1, "64");
            GLOAD16(Wn[2], pW1, "128"); GLOAD16(Wn[3], pW1, "192");
            GLOAD16(Wn[4], pW1, "256"); GLOAD16(Wn[5], pW1, "320");
            GLOAD16(Wn[6], pW1, "384"); GLOAD16(Wn[7], pW1, "448");
            GLOAD16(Wn[8], pW1, "512"); GLOAD16(Wn[9], pW1, "576");
            GLOADF(b1n, pb1);
            pW2a += 64; pW2b += 64; pW2c += 64; pW2d += 64;
            pW1 += (size_t)64 * XD; pb1 += 64;

            VMWAIT("19");  // W1(oc)+b1(oc) done; 19 newer still in flight

            // GEMM1: pre[64 tok][16 cols per wave], K=320
            f32x4 pre[4];
            #pragma unroll
            for (int mi = 0; mi < 4; ++mi) pre[mi] = (f32x4){0.f, 0.f, 0.f, 0.f};
            #pragma unroll
            for (int ks = 0; ks < 10; ++ks) {
                #pragma unroll
                for (int mi = 0; mi < 4; ++mi) {
                    short8 a = *(const short8*)&xs[(mi * 16 + l15) * 320 + (((ks * 4 + kg) ^ lr7) << 3)];
                    pre[mi] = __builtin_amdgcn_mfma_f32_16x16x32_bf16(a, Wc[ks], pre[mi], 0, 0, 0);
                }
            }
            // bias + tanh-GELU -> hsbuf (swizzled scalar writes)
            {
                const int cgb = 2 * wv + (l15 >> 3);
                #pragma unroll
                for (int mi = 0; mi < 4; ++mi) {
                    #pragma unroll
                    for (int r = 0; r < 4; ++r) {
                        float v = pre[mi][r] + b1c;
                        float y = 1.5957691216057308f * v * fmaf(v * v, 0.044715f, 1.0f);
                        float gl = __fdividef(v, 1.0f + __expf(-y));
                        int row = mi * 16 + kg * 4 + r;
                        int cg = cgb ^ (row & 7);
                        hsbuf[row * 64 + (cg << 3) + lr7] = __float2bfloat16(gl);
                    }
                }
            }
            wg_barrier();   // hs(oc) visible to all waves
            VMWAIT("11");   // W2(oc) done; next W1+b1 (11) still in flight

            // GEMM2: acc += hid @ W2^T over this oc's K=64 slice
            #pragma unroll
            for (int ks = 0; ks < 2; ++ks) {
                short8 a2[4];
                #pragma unroll
                for (int mi = 0; mi < 4; ++mi)
                    a2[mi] = *(const short8*)&hsbuf[(mi * 16 + l15) * 64 + (((ks * 4 + kg) ^ lr7) << 3)];
                #pragma unroll
                for (int nf = 0; nf < 4; ++nf)
                    #pragma unroll
                    for (int mi = 0; mi < 4; ++mi)
                        acc[mi][nf] = __builtin_amdgcn_mfma_f32_16x16x32_bf16(a2[mi], f2[nf * 2 + ks], acc[mi][nf], 0, 0, 0);
            }
        };

        #pragma unroll 1
        for (int t = 0; t < 8; ++t) {
            ocbody(Wa, Wb, bA, bB, hsbufs[0]);
            ocbody(Wb, Wa, bB, bA, hsbufs[1]);
        }

        // epilogue: +b2, *routing weight, scatter bf16 rows to per-pair scratch
        #pragma unroll
        for (int r = 0; r < 4; ++r) {
            int row = kg * 4 + r;
            #pragma unroll
            for (int mi = 0; mi < 4; ++mi) {
                int rr = mi * 16 + row;
                if (rr < nv) {
                    int pair = list[e * BB + base + rr];
                    float w = topw[pair];
                    __hip_bfloat16* dst = tmp + (size_t)pair * HH + wv * 64;
                    #pragma unroll
                    for (int nf = 0; nf < 4; ++nf) {
                        int d = wv * 64 + nf * 16 + l15;
                        dst[nf * 16 + l15] = __float2bfloat16(w * (acc[mi][nf][r] + b2[e * HH + d]));
                    }
                }
            }
        }
        // next gather is ordered by the last oc barrier
    }
}

// ---------------- combine the two expert slots (bf16 tmp -> f32 out) ----------------
__global__ void combine_kernel(const __hip_bfloat16* __restrict__ tmp, float* __restrict__ out) {
    int i = blockIdx.x * blockDim.x + threadIdx.x;  // float4 index over [B*256/4)
    int b = i >> 6;
    int d4 = i & 63;
    const ushort4* t0 = (const ushort4*)(tmp + (size_t)b * 512);
    ushort4 a = t0[d4];
    ushort4 c = t0[64 + d4];
    union { unsigned short u; __hip_bfloat16 b; } cv;
    float4 o;
    { cv.u = a.x; float fa = __bfloat162float(cv.b); cv.u = c.x; o.x = fa + __bfloat162float(cv.b); }
    { cv.u = a.y; float fa = __bfloat162float(cv.b); cv.u = c.y; o.y = fa + __bfloat162float(cv.b); }
    { cv.u = a.z; float fa = __bfloat162float(cv.b); cv.u = c.z; o.z = fa + __bfloat162float(cv.b); }
    { cv.u = a.w; float fa = __bfloat162float(cv.b); cv.u = c.w; o.w = fa + __bfloat162float(cv.b); }
    ((float4*)out)[i] = o;
}

extern "C" void kernel_launch(void* const* d_in, const int* in_sizes, int n_in,
                              void* d_out, int out_size, void* d_ws, size_t ws_size,
                              hipStream_t stream) {
    const float* h   = (const float*)d_in[0];
    const float* ce  = (const float*)d_in[1];
    const float* anc = (const float*)d_in[2];
    const float* W1  = (const float*)d_in[3];
    const float* b1  = (const float*)d_in[4];
    const float* W2  = (const float*)d_in[5];
    const float* b2  = (const float*)d_in[6];
    const float* gum = (const float*)d_in[7];
    float* out = (float*)d_out;

    char* ws = (char*)d_ws;
    size_t off = 0;
    auto alloc = [&](size_t bytes) {
        char* p = ws + off;
        off = (off + bytes + 255) & ~(size_t)255;
        return p;
    };
    __hip_bfloat16* W1bf = (__hip_bfloat16*)alloc((size_t)EE * FH * XD * 2);
    __hip_bfloat16* W2bf = (__hip_bfloat16*)alloc((size_t)EE * HH * FH * 2);
    __hip_bfloat16* xbf  = (__hip_bfloat16*)alloc((size_t)BB * XD * 2);
    __hip_bfloat16* tmp  = (__hip_bfloat16*)alloc((size_t)BB * 2 * HH * 2);
    float* topw = (float*)alloc((size_t)BB * 2 * 4);
    int*   tope = (int*)alloc((size_t)BB * 2 * 4);
    int*   list = (int*)alloc((size_t)EE * BB * 4);
    int*   cnt  = (int*)alloc(EE * CNTP * 4);
    float* anorm = (float*)alloc(EE * CC * 4);
    float* partial = (float*)alloc(64 * EE * 4);

    hipMemsetAsync(cnt, 0, EE * CNTP * 4, stream);
    anorm_kernel<<<1, 256, 0, stream>>>(anc, anorm);
    router_kernel<<<BB / 16, 256, 0, stream>>>(ce, gum, anorm, topw, tope);
    assign_kernel<<<2 * BB / 512, 256, 0, stream>>>(tope, list, cnt);
    convert_w_kernel<<<((EE * FH * XD + EE * HH * FH) / 4 + 255) / 256, 256, 0, stream>>>(W1, W2, W1bf, W2bf);
    convert_x_kernel<<<(BB * XD / 4 + 255) / 256, 256, 0, stream>>>(h, ce, xbf);
    aux_partial_kernel<<<64, 256, 0, stream>>>(topw, tope, partial);
    aux_final_kernel<<<1, 64, 0, stream>>>(partial, out);
    moe_kernel<<<dim3(EE, 36), 256, 0, stream>>>(xbf, W1bf, W2bf, b1, b2, list, cnt, topw, tmp);
    combine_kernel<<<(BB * HH / 4) / 256, 256, 0, stream>>>(tmp, out);
}

// Round 6
// 183.659 us; speedup vs baseline: 2.7687x; 1.0738x over previous
//
#include <hip/hip_runtime.h>
#include <hip/hip_bf16.h>

#define BB 16384
#define EE 16
#define HH 256
#define CC 64
#define XD 320   // H + C
#define FH 1024  // 4H
#define CNTP 16  // cnt padding stride (one counter per 64B line)

typedef __attribute__((ext_vector_type(8))) short short8;
typedef __attribute__((ext_vector_type(4))) float f32x4;

// asm global loads with exact manual vmcnt accounting (T3/T4)
#define GLOAD16(dst, a, OFF) \
    asm volatile("global_load_dwordx4 %0, %1, off offset:" OFF : "=&v"(dst) : "v"(a))
#define GLOADF(dst, a) \
    asm volatile("global_load_dword %0, %1, off" : "=&v"(dst) : "v"(a))
#define VMWAIT(N) do { asm volatile("s_waitcnt vmcnt(" N ")" ::: "memory"); \
                       __builtin_amdgcn_sched_barrier(0); } while (0)

__device__ inline unsigned short bfu(float x) {
    union { __hip_bfloat16 b; unsigned short u; } c;
    c.b = __float2bfloat16(x);
    return c.u;
}

// raw workgroup barrier: drains LDS ops only, leaves global loads in flight
__device__ inline void wg_barrier() {
    asm volatile("s_waitcnt lgkmcnt(0)" ::: "memory");
    __builtin_amdgcn_s_barrier();
    asm volatile("" ::: "memory");
}

// ---------------- anchor normalize ----------------
__global__ void anorm_kernel(const float* __restrict__ anchor, float* __restrict__ anorm) {
    int lane = threadIdx.x & 63;
    int wv = threadIdx.x >> 6;
    for (int e = wv; e < EE; e += 4) {
        float a = anchor[e * CC + lane];
        float s = a * a;
        #pragma unroll
        for (int off = 1; off < 64; off <<= 1) s += __shfl_xor(s, off, 64);
        anorm[e * CC + lane] = a / fmaxf(sqrtf(s), 1e-8f);
    }
}

// ---------------- router: 16 tokens x 16 experts per block, no atomics ----------------
__global__ __launch_bounds__(256) void router_kernel(
    const float* __restrict__ code_emb, const float* __restrict__ gumbel,
    const float* __restrict__ anorm,
    float* __restrict__ topw, int* __restrict__ tope)
{
    __shared__ float an_s[EE][68];
    __shared__ float ce_s[16][68];
    __shared__ float inrm[16];
    const int tid = threadIdx.x;

    {
        int idx = tid * 4;
        int r = idx >> 6, k = idx & 63;
        *(float4*)&an_s[r][k] = *(const float4*)&anorm[idx];
        *(float4*)&ce_s[r][k] = *(const float4*)&code_emb[blockIdx.x * 1024 + idx];
    }
    __syncthreads();

    const int tok = tid >> 4;
    const int e = tid & 15;
    if (e == 0) {
        float s = 0.f;
        #pragma unroll
        for (int k = 0; k < 64; ++k) { float c = ce_s[tok][k]; s += c * c; }
        inrm[tok] = 0.125f / fmaxf(sqrtf(s), 1e-8f);
    }
    __syncthreads();

    float dot = 0.f;
    #pragma unroll
    for (int k = 0; k < 64; ++k) dot += ce_s[tok][k] * an_s[e][k];

    const int b = blockIdx.x * 16 + tok;
    float z = (dot * inrm[tok] + gumbel[b * EE + e]) * 2.0f;  // /TAU, TAU=0.5

    float m = z;
    #pragma unroll
    for (int off = 1; off < 16; off <<= 1) m = fmaxf(m, __shfl_xor(m, off, 64));
    float p = expf(z - m);
    float s = p;
    #pragma unroll
    for (int off = 1; off < 16; off <<= 1) s += __shfl_xor(s, off, 64);
    float w = p / s;

    const int lbase = (tid & 63) & 48;
    float best = -1.f, second = -1.f;
    int bi = 0, si = 0;
    #pragma unroll
    for (int j = 0; j < EE; ++j) {
        float wj = __shfl(w, lbase + j, 64);
        if (wj > best) { second = best; si = bi; best = wj; bi = j; }
        else if (wj > second) { second = wj; si = j; }
    }
    if (e == 0) {
        topw[b * 2] = best;       tope[b * 2] = bi;
        topw[b * 2 + 1] = second; tope[b * 2 + 1] = si;
    }
}

// ---------------- counting-sort assignment: 512 pairs per block ----------------
__global__ __launch_bounds__(256) void assign_kernel(
    const int* __restrict__ tope, int* __restrict__ list, int* __restrict__ cnt)
{
    __shared__ int lcnt[EE];
    __shared__ int base[EE];
    const int tid = threadIdx.x;
    if (tid < EE) lcnt[tid] = 0;
    __syncthreads();
    const int p0 = blockIdx.x * 512;
    const int e0 = tope[p0 + tid];
    const int e1 = tope[p0 + 256 + tid];
    const int r0 = atomicAdd(&lcnt[e0], 1);
    const int r1 = atomicAdd(&lcnt[e1], 1);
    __syncthreads();
    if (tid < EE) base[tid] = atomicAdd(&cnt[tid * CNTP], lcnt[tid]);
    __syncthreads();
    list[e0 * BB + base[e0] + r0] = p0 + tid;
    list[e1 * BB + base[e1] + r1] = p0 + 256 + tid;
}

// ---------------- weight conversion f32 -> bf16 ----------------
__global__ void convert_w_kernel(const float* __restrict__ W1, const float* __restrict__ W2,
                                 __hip_bfloat16* __restrict__ W1bf, __hip_bfloat16* __restrict__ W2bf) {
    int i = blockIdx.x * blockDim.x + threadIdx.x;
    const int n1 = EE * FH * XD / 4;
    const int n2 = EE * HH * FH / 4;
    if (i < n1) {
        float4 v = ((const float4*)W1)[i];
        ushort4 o; o.x = bfu(v.x); o.y = bfu(v.y); o.z = bfu(v.z); o.w = bfu(v.w);
        ((ushort4*)W1bf)[i] = o;
    } else if (i < n1 + n2) {
        int j = i - n1;
        float4 v = ((const float4*)W2)[j];
        ushort4 o; o.x = bfu(v.x); o.y = bfu(v.y); o.z = bfu(v.z); o.w = bfu(v.w);
        ((ushort4*)W2bf)[j] = o;
    }
}

// ---------------- x = concat(h, code_emb) -> bf16 ----------------
__global__ void convert_x_kernel(const float* __restrict__ h, const float* __restrict__ ce,
                                 __hip_bfloat16* __restrict__ xbf) {
    int i = blockIdx.x * blockDim.x + threadIdx.x;
    const int n = BB * XD / 4;
    if (i >= n) return;
    int i4 = i * 4;
    int b = i4 / XD;
    int c = i4 % XD;
    float4 v;
    if (c < HH) v = *(const float4*)&h[b * HH + c];
    else        v = *(const float4*)&ce[b * CC + (c - HH)];
    ushort4 o; o.x = bfu(v.x); o.y = bfu(v.y); o.z = bfu(v.z); o.w = bfu(v.w);
    ((ushort4*)xbf)[i] = o;
}

// ---------------- aux loss: 64-block partial + tiny final (deterministic) ----------------
__global__ __launch_bounds__(256) void aux_partial_kernel(const float* __restrict__ topw,
                                                          const int* __restrict__ tope,
                                                          float* __restrict__ partial) {
    __shared__ float ls[256][EE + 1];
    int tid = threadIdx.x;
    #pragma unroll
    for (int e = 0; e < EE; ++e) ls[tid][e] = 0.f;
    int i0 = blockIdx.x * 512 + tid;
    ls[tid][tope[i0]] += topw[i0];
    ls[tid][tope[i0 + 256]] += topw[i0 + 256];
    __syncthreads();
    if (tid < EE) {
        float s = 0.f;
        for (int r = 0; r < 256; ++r) s += ls[r][tid];
        partial[blockIdx.x * EE + tid] = s;
    }
}

__global__ void aux_final_kernel(const float* __restrict__ partial, float* __restrict__ out) {
    __shared__ float counts[EE];
    int tid = threadIdx.x;
    if (tid < EE) {
        float s = 0.f;
        for (int bk = 0; bk < 64; ++bk) s += partial[bk * EE + tid];
        counts[tid] = s;
    }
    __syncthreads();
    if (tid == 0) {
        float total = 0.f;
        for (int e = 0; e < EE; ++e) total += counts[e];
        float mean = total / EE;
        float var = 0.f;
        for (int e = 0; e < EE; ++e) { float d = counts[e] - mean; var += d * d; }
        var /= (EE - 1);
        float ent = 0.f;
        for (int e = 0; e < EE; ++e) { float ld = counts[e] / total; ent -= ld * logf(ld + 1e-12f); }
        out[(size_t)BB * HH] = 0.5f * (sqrtf(var) + ent);
    }
}

// ---------------- fused sparse MoE MLP (spill-free pipeline + XCD-pinned) ----------------
// 1-D grid of 512 blocks: bid = t*16 + e, so bid%8 == e%8 -> all blocks of
// expert e land on XCD e%8; its L2 (4MB) holds the 2 resident experts' 2.36MB
// of weights -> weight re-reads are local L2 hits.
// Single-buffered W1 in regs (consumed before re-issue), batch per oc:
// [10xW1(oc+1)+1xb1(oc+1)] after GEMM1, [8xW2(oc+1)] after GEMM2.
// Invariant queue at loop top: [W1+b1 (11 oldest), f2 (8)] -> VMWAIT(8);
// after W1-issue: [f2 (8 oldest), W1'+b1' (11)] -> VMWAIT(11) before GEMM2.
__global__ __launch_bounds__(256, 2) void moe_kernel(
    const __hip_bfloat16* __restrict__ xbf,
    const __hip_bfloat16* __restrict__ W1bf,
    const __hip_bfloat16* __restrict__ W2bf,
    const float* __restrict__ b1, const float* __restrict__ b2,
    const int* __restrict__ list, const int* __restrict__ cnt,
    const float* __restrict__ topw,
    __hip_bfloat16* __restrict__ tmp)
{
    __shared__ __hip_bfloat16 xs[64 * 320];
    __shared__ __hip_bfloat16 hsbufs[2][64 * 64];
    const int e = blockIdx.x & 15;   // expert; XCD = bid%8 = e%8
    const int t0 = blockIdx.x >> 4;  // starting tile index
    const int n = cnt[e * CNTP];
    const int tid = threadIdx.x;
    const int lane = tid & 63;
    const int wv = tid >> 6;     // 0..3
    const int l15 = lane & 15;
    const int kg = lane >> 4;    // 0..3
    const int lr7 = l15 & 7;

    const __hip_bfloat16* w1e = W1bf + (size_t)e * FH * XD;
    const __hip_bfloat16* w2e = W2bf + (size_t)e * HH * FH;
    const __hip_bfloat16* w1r = w1e + (size_t)(wv * 16 + l15) * XD + kg * 8;
    const __hip_bfloat16* w2r = w2e + (size_t)(wv * 64 + l15) * FH + kg * 8;
    const float* b1r = b1 + e * FH + wv * 16 + l15;

    // b2 preload (compiler loads; flushed before the asm pipeline starts)
    float b2v[4];
    #pragma unroll
    for (int nf = 0; nf < 4; ++nf) b2v[nf] = b2[e * HH + wv * 64 + nf * 16 + l15];

    short8 Wc[10], f2[8];
    float bA, bB;
    const __hip_bfloat16 *pW1, *pW2a, *pW2b, *pW2c, *pW2d;
    const float* pb1;
    f32x4 acc[4][4];

    auto ocbody = [&](int oc, __hip_bfloat16* hsbuf, float& b1c, float& b1n) {
        VMWAIT("8");  // W1(oc)+b1(oc) retired; f2(oc) (8) stays in flight

        // GEMM1: pre[64 tok][16 cols per wave], K=320
        f32x4 pre[4];
        #pragma unroll
        for (int mi = 0; mi < 4; ++mi) pre[mi] = (f32x4){0.f, 0.f, 0.f, 0.f};
        #pragma unroll
        for (int ks = 0; ks < 10; ++ks) {
            #pragma unroll
            for (int mi = 0; mi < 4; ++mi) {
                short8 a = *(const short8*)&xs[(mi * 16 + l15) * 320 + (((ks * 4 + kg) ^ lr7) << 3)];
                pre[mi] = __builtin_amdgcn_mfma_f32_16x16x32_bf16(a, Wc[ks], pre[mi], 0, 0, 0);
            }
        }
        // issue W1(oc+1) + b1(oc+1): flies across GELU+barrier+GEMM2
        GLOAD16(Wc[0], pW1, "0");   GLOAD16(Wc[1], pW1, "64");
        GLOAD16(Wc[2], pW1, "128"); GLOAD16(Wc[3], pW1, "192");
        GLOAD16(Wc[4], pW1, "256"); GLOAD16(Wc[5], pW1, "320");
        GLOAD16(Wc[6], pW1, "384"); GLOAD16(Wc[7], pW1, "448");
        GLOAD16(Wc[8], pW1, "512"); GLOAD16(Wc[9], pW1, "576");
        GLOADF(b1n, pb1);
        pW1 = (oc == 14) ? w1r : pW1 + (size_t)64 * XD;
        pb1 = (oc == 14) ? b1r : pb1 + 64;

        // bias + tanh-GELU -> hsbuf (swizzled)
        {
            const int cgb = 2 * wv + (l15 >> 3);
            #pragma unroll
            for (int mi = 0; mi < 4; ++mi) {
                #pragma unroll
                for (int r = 0; r < 4; ++r) {
                    float v = pre[mi][r] + b1c;
                    float y = 1.5957691216057308f * v * fmaf(v * v, 0.044715f, 1.0f);
                    float gl = __fdividef(v, 1.0f + __expf(-y));
                    int row = mi * 16 + kg * 4 + r;
                    int cg = cgb ^ (row & 7);
                    hsbuf[row * 64 + (cg << 3) + lr7] = __float2bfloat16(gl);
                }
            }
        }
        wg_barrier();   // hs(oc) visible to all waves
        VMWAIT("11");   // f2(oc) retired; W1(oc+1)+b1(oc+1) (11) stay in flight

        // GEMM2: acc += hid @ W2^T over this oc's K=64 slice
        #pragma unroll
        for (int ks = 0; ks < 2; ++ks) {
            short8 a2[4];
            #pragma unroll
            for (int mi = 0; mi < 4; ++mi)
                a2[mi] = *(const short8*)&hsbuf[(mi * 16 + l15) * 64 + (((ks * 4 + kg) ^ lr7) << 3)];
            #pragma unroll
            for (int nf = 0; nf < 4; ++nf)
                #pragma unroll
                for (int mi = 0; mi < 4; ++mi)
                    acc[mi][nf] = __builtin_amdgcn_mfma_f32_16x16x32_bf16(a2[mi], f2[nf * 2 + ks], acc[mi][nf], 0, 0, 0);
        }
        // issue f2(oc+1)
        GLOAD16(f2[0], pW2a, "0"); GLOAD16(f2[1], pW2a, "64");
        GLOAD16(f2[2], pW2b, "0"); GLOAD16(f2[3], pW2b, "64");
        GLOAD16(f2[4], pW2c, "0"); GLOAD16(f2[5], pW2c, "64");
        GLOAD16(f2[6], pW2d, "0"); GLOAD16(f2[7], pW2d, "64");
        pW2a = (oc == 14) ? w2r : pW2a + 64;
        pW2b = (oc == 14) ? w2r + (size_t)16 * FH : pW2b + 64;
        pW2c = (oc == 14) ? w2r + (size_t)32 * FH : pW2c + 64;
        pW2d = (oc == 14) ? w2r + (size_t)48 * FH : pW2d + 64;
    };

    bool first = true;
    for (int tile = t0; tile * 64 < n; tile += 32) {
        const int base = tile * 64;
        const int nv = min(64, n - base);

        // gather 64 x-rows into swizzled xs: 4 threads/row, 10x16B each
        {
            int row = tid >> 2, part = tid & 3;
            int pr = list[e * BB + base + min(row, nv - 1)];
            const ulonglong2* src = (const ulonglong2*)(xbf + (size_t)(pr >> 1) * XD) + part * 10;
            int r7 = row & 7;
            #pragma unroll
            for (int i = 0; i < 10; ++i) {
                int u = part * 10 + i;
                *(ulonglong2*)&xs[row * 320 + ((u ^ r7) << 3)] = src[i];
            }
        }
        wg_barrier();  // xs ready

        if (first) {
            first = false;
            asm volatile("s_waitcnt vmcnt(0)" ::: "memory");  // flush compiler loads
            __builtin_amdgcn_sched_barrier(0);
            // prologue: W1(0)+b1(0) then f2(0)  -> queue [11, 8]
            GLOAD16(Wc[0], w1r, "0");   GLOAD16(Wc[1], w1r, "64");
            GLOAD16(Wc[2], w1r, "128"); GLOAD16(Wc[3], w1r, "192");
            GLOAD16(Wc[4], w1r, "256"); GLOAD16(Wc[5], w1r, "320");
            GLOAD16(Wc[6], w1r, "384"); GLOAD16(Wc[7], w1r, "448");
            GLOAD16(Wc[8], w1r, "512"); GLOAD16(Wc[9], w1r, "576");
            GLOADF(bA, b1r);
            const __hip_bfloat16* q0 = w2r;
            const __hip_bfloat16* q1 = w2r + (size_t)16 * FH;
            const __hip_bfloat16* q2 = w2r + (size_t)32 * FH;
            const __hip_bfloat16* q3 = w2r + (size_t)48 * FH;
            GLOAD16(f2[0], q0, "0"); GLOAD16(f2[1], q0, "64");
            GLOAD16(f2[2], q1, "0"); GLOAD16(f2[3], q1, "64");
            GLOAD16(f2[4], q2, "0"); GLOAD16(f2[5], q2, "64");
            GLOAD16(f2[6], q3, "0"); GLOAD16(f2[7], q3, "64");
            pW1 = w1r + (size_t)64 * XD;
            pb1 = b1r + 64;
            pW2a = q0 + 64; pW2b = q1 + 64; pW2c = q2 + 64; pW2d = q3 + 64;
        }

        #pragma unroll
        for (int mi = 0; mi < 4; ++mi)
            #pragma unroll
            for (int nf = 0; nf < 4; ++nf)
                acc[mi][nf] = (f32x4){0.f, 0.f, 0.f, 0.f};

        #pragma unroll 1
        for (int tt = 0; tt < 8; ++tt) {
            ocbody(2 * tt,     hsbufs[0], bA, bB);
            ocbody(2 * tt + 1, hsbufs[1], bB, bA);
        }
        // wrap-around issues already loaded W1(0)'+b1(0)'+f2(0)' for the next tile

        // epilogue: +b2, *routing weight, scatter bf16 rows to per-pair scratch
        #pragma unroll
        for (int r = 0; r < 4; ++r) {
            #pragma unroll
            for (int mi = 0; mi < 4; ++mi) {
                int rr = mi * 16 + kg * 4 + r;
                if (rr < nv) {
                    int pair = list[e * BB + base + rr];
                    float w = topw[pair];
                    __hip_bfloat16* dst = tmp + (size_t)pair * HH + wv * 64;
                    #pragma unroll
                    for (int nf = 0; nf < 4; ++nf)
                        dst[nf * 16 + l15] = __float2bfloat16(w * (acc[mi][nf][r] + b2v[nf]));
                }
            }
        }
        // next gather is ordered by the last oc barrier
    }
}

// ---------------- combine the two expert slots (bf16 tmp -> f32 out) ----------------
__global__ void combine_kernel(const __hip_bfloat16* __restrict__ tmp, float* __restrict__ out) {
    int i = blockIdx.x * blockDim.x + threadIdx.x;  // float4 index over [B*256/4)
    int b = i >> 6;
    int d4 = i & 63;
    const ushort4* t0 = (const ushort4*)(tmp + (size_t)b * 512);
    ushort4 a = t0[d4];
    ushort4 c = t0[64 + d4];
    union { unsigned short u; __hip_bfloat16 b; } cv;
    float4 o;
    { cv.u = a.x; float fa = __bfloat162float(cv.b); cv.u = c.x; o.x = fa + __bfloat162float(cv.b); }
    { cv.u = a.y; float fa = __bfloat162float(cv.b); cv.u = c.y; o.y = fa + __bfloat162float(cv.b); }
    { cv.u = a.z; float fa = __bfloat162float(cv.b); cv.u = c.z; o.z = fa + __bfloat162float(cv.b); }
    { cv.u = a.w; float fa = __bfloat162float(cv.b); cv.u = c.w; o.w = fa + __bfloat162float(cv.b); }
    ((float4*)out)[i] = o;
}

extern "C" void kernel_launch(void* const* d_in, const int* in_sizes, int n_in,
                              void* d_out, int out_size, void* d_ws, size_t ws_size,
                              hipStream_t stream) {
    const float* h   = (const float*)d_in[0];
    const float* ce  = (const float*)d_in[1];
    const float* anc = (const float*)d_in[2];
    const float* W1  = (const float*)d_in[3];
    const float* b1  = (const float*)d_in[4];
    const float* W2  = (const float*)d_in[5];
    const float* b2  = (const float*)d_in[6];
    const float* gum = (const float*)d_in[7];
    float* out = (float*)d_out;

    char* ws = (char*)d_ws;
    size_t off = 0;
    auto alloc = [&](size_t bytes) {
        char* p = ws + off;
        off = (off + bytes + 255) & ~(size_t)255;
        return p;
    };
    __hip_bfloat16* W1bf = (__hip_bfloat16*)alloc((size_t)EE * FH * XD * 2);
    __hip_bfloat16* W2bf = (__hip_bfloat16*)alloc((size_t)EE * HH * FH * 2);
    __hip_bfloat16* xbf  = (__hip_bfloat16*)alloc((size_t)BB * XD * 2);
    __hip_bfloat16* tmp  = (__hip_bfloat16*)alloc((size_t)BB * 2 * HH * 2);
    float* topw = (float*)alloc((size_t)BB * 2 * 4);
    int*   tope = (int*)alloc((size_t)BB * 2 * 4);
    int*   list = (int*)alloc((size_t)EE * BB * 4);
    int*   cnt  = (int*)alloc(EE * CNTP * 4);
    float* anorm = (float*)alloc(EE * CC * 4);
    float* partial = (float*)alloc(64 * EE * 4);

    hipMemsetAsync(cnt, 0, EE * CNTP * 4, stream);
    anorm_kernel<<<1, 256, 0, stream>>>(anc, anorm);
    router_kernel<<<BB / 16, 256, 0, stream>>>(ce, gum, anorm, topw, tope);
    assign_kernel<<<2 * BB / 512, 256, 0, stream>>>(tope, list, cnt);
    convert_w_kernel<<<((EE * FH * XD + EE * HH * FH) / 4 + 255) / 256, 256, 0, stream>>>(W1, W2, W1bf, W2bf);
    convert_x_kernel<<<(BB * XD / 4 + 255) / 256, 256, 0, stream>>>(h, ce, xbf);
    aux_partial_kernel<<<64, 256, 0, stream>>>(topw, tope, partial);
    aux_final_kernel<<<1, 64, 0, stream>>>(partial, out);
    moe_kernel<<<dim3(EE * 32), 256, 0, stream>>>(xbf, W1bf, W2bf, b1, b2, list, cnt, topw, tmp);
    combine_kernel<<<(BB * HH / 4) / 256, 256, 0, stream>>>(tmp, out);
}